// Round 1
// baseline (1116.112 us; speedup 1.0000x reference)
//
#include <hip/hip_runtime.h>
#include <math.h>

#define B_ 32
#define N_ 1024
#define D_ 256
#define K_ 8
#define CAND 12

// ---------------- Kernel 1: per-token inverse norms (fp64) ----------------
__global__ __launch_bounds__(256) void norm_kernel(const float* __restrict__ tok,
                                                   double* __restrict__ invn) {
    const int tid = threadIdx.x;
    const int wave = tid >> 6, lane = tid & 63;
    const int row = blockIdx.x * 4 + wave;            // 32768 rows total
    const float* p = tok + (size_t)row * D_;
    const float4 v = *reinterpret_cast<const float4*>(p + lane * 4);
    double s = (double)v.x * v.x + (double)v.y * v.y +
               (double)v.z * v.z + (double)v.w * v.w;
    #pragma unroll
    for (int off = 32; off > 0; off >>= 1) s += __shfl_xor(s, off, 64);
    if (lane == 0) invn[row] = 1.0 / (sqrt(s) + 1e-8);
}

// ---------------- Kernel 2: tiled sim + fused top-12 + fp64 rescore -------
// grid (16, 32): blockIdx.x = i-tile (64 rows), blockIdx.y = batch
__global__ __launch_bounds__(256) void sim_topk_kernel(const float* __restrict__ tok,
                                                       const double* __restrict__ invn,
                                                       int* __restrict__ topk) {
    __shared__ float As[64][68];   // A^T chunk: [k][i], pad 68 -> conflict-free b128
    __shared__ float Bs[64][68];   // B^T chunk: [k][j]
    __shared__ float Sim[64][66];  // sim tile [i][j], stride 66 -> 2-way (free)

    const int b  = blockIdx.y;
    const int i0 = blockIdx.x * 64;
    const int tid = threadIdx.x;
    const int tx = tid & 15, ty = tid >> 4;
    const float*  tokB = tok  + (size_t)b * N_ * D_;
    const double* invB = invn + b * N_;

    float fi[4];
    #pragma unroll
    for (int ii = 0; ii < 4; ++ii) fi[ii] = (float)invB[i0 + ty * 4 + ii];

    const int r = tid >> 2, q = tid & 3;   // staging: row r, quarter q

    // per-row top-12, sorted descending, kept in registers (static indexing only)
    float vals[CAND]; int idxs[CAND];
    #pragma unroll
    for (int c = 0; c < CAND; ++c) { vals[c] = -INFINITY; idxs[c] = -1; }

    for (int jt = 0; jt < 16; ++jt) {
        const int j0 = jt * 64;
        float acc[4][4];
        #pragma unroll
        for (int ii = 0; ii < 4; ++ii)
            #pragma unroll
            for (int jj = 0; jj < 4; ++jj) acc[ii][jj] = 0.0f;

        for (int kc = 0; kc < 4; ++kc) {
            const int k0 = kc * 64;
            __syncthreads();   // protect As/Bs reuse
            const float* pa = tokB + (size_t)(i0 + r) * D_ + k0 + q * 16;
            const float* pb = tokB + (size_t)(j0 + r) * D_ + k0 + q * 16;
            #pragma unroll
            for (int s = 0; s < 4; ++s) {
                const float4 va = *reinterpret_cast<const float4*>(pa + s * 4);
                const float4 vb = *reinterpret_cast<const float4*>(pb + s * 4);
                const int kk = q * 16 + s * 4;
                As[kk + 0][r] = va.x; As[kk + 1][r] = va.y;
                As[kk + 2][r] = va.z; As[kk + 3][r] = va.w;
                Bs[kk + 0][r] = vb.x; Bs[kk + 1][r] = vb.y;
                Bs[kk + 2][r] = vb.z; Bs[kk + 3][r] = vb.w;
            }
            __syncthreads();
            #pragma unroll 8
            for (int k = 0; k < 64; ++k) {
                const float4 a4 = *reinterpret_cast<const float4*>(&As[k][ty * 4]);
                const float4 b4 = *reinterpret_cast<const float4*>(&Bs[k][tx * 4]);
                const float av[4] = {a4.x, a4.y, a4.z, a4.w};
                const float bv[4] = {b4.x, b4.y, b4.z, b4.w};
                #pragma unroll
                for (int ii = 0; ii < 4; ++ii)
                    #pragma unroll
                    for (int jj = 0; jj < 4; ++jj)
                        acc[ii][jj] = fmaf(av[ii], bv[jj], acc[ii][jj]);
            }
        }

        // scale by inverse norms, write sim tile to LDS
        float fj[4];
        #pragma unroll
        for (int jj = 0; jj < 4; ++jj) fj[jj] = (float)invB[j0 + tx * 4 + jj];
        #pragma unroll
        for (int ii = 0; ii < 4; ++ii)
            #pragma unroll
            for (int jj = 0; jj < 4; ++jj)
                Sim[ty * 4 + ii][tx * 4 + jj] = acc[ii][jj] * fi[ii] * fj[jj];
        __syncthreads();

        // per-row candidate scan: thread t owns row t (t < 64)
        if (tid < 64) {
            const int gi = i0 + tid;
            for (int jl = 0; jl < 64; ++jl) {
                const int gj = j0 + jl;
                const float v = Sim[tid][jl];
                if (gj != gi && v > vals[CAND - 1]) {
                    float cv = v; int ci = gj;
                    #pragma unroll
                    for (int c = 0; c < CAND; ++c) {
                        if (cv > vals[c]) {
                            const float tv = vals[c]; vals[c] = cv; cv = tv;
                            const int   ti = idxs[c]; idxs[c] = ci; ci = ti;
                        }
                    }
                }
            }
        }
    }

    // fp64 rescore of the 12 candidates -> exact top-8
    if (tid < 64) {
        const int gi = i0 + tid;
        const float* qi = tokB + (size_t)gi * D_;
        const double di = invB[gi];
        double dv[CAND];
        #pragma unroll 1
        for (int c = 0; c < CAND; ++c) {
            const float* qj = tokB + (size_t)idxs[c] * D_;
            double s = 0.0;
            for (int d = 0; d < D_; d += 4) {
                const float4 x = *reinterpret_cast<const float4*>(qi + d);
                const float4 y = *reinterpret_cast<const float4*>(qj + d);
                s += (double)x.x * y.x + (double)x.y * y.y +
                     (double)x.z * y.z + (double)x.w * y.w;
            }
            dv[c] = s * di * invB[idxs[c]];
        }
        const int out_base = (b * N_ + gi) * K_;
        // rank-based top-8 (ties -> lower index, matching lax.top_k)
        #pragma unroll
        for (int c = 0; c < CAND; ++c) {
            int rank = 0;
            #pragma unroll
            for (int c2 = 0; c2 < CAND; ++c2) {
                if (c2 == c) continue;
                if (dv[c2] > dv[c] || (dv[c2] == dv[c] && idxs[c2] < idxs[c])) ++rank;
            }
            if (rank < K_) topk[out_base + rank] = idxs[c];
        }
    }
}

// ---------------- Kernel 3: mutual filter + scatter 1.0 -------------------
__global__ __launch_bounds__(256) void mutual_kernel(const int* __restrict__ topk,
                                                     float* __restrict__ out) {
    const int gid = blockIdx.x * 256 + threadIdx.x;   // 32768*8 threads
    const int row = gid >> 3, s = gid & 7;
    const int j = topk[row * K_ + s];
    const int b = row >> 10, i = row & (N_ - 1);
    const int* tj = topk + ((b << 10) + j) * K_;
    bool m = false;
    #pragma unroll
    for (int u = 0; u < K_; ++u) m = m || (tj[u] == i);
    if (m) out[(size_t)row * N_ + j] = 1.0f;
}

extern "C" void kernel_launch(void* const* d_in, const int* in_sizes, int n_in,
                              void* d_out, int out_size, void* d_ws, size_t ws_size,
                              hipStream_t stream) {
    const float* tok = (const float*)d_in[0];
    float* out = (float*)d_out;
    double* invn = (double*)d_ws;                                  // 32768 * 8 B
    int* topk = (int*)((char*)d_ws + (size_t)B_ * N_ * sizeof(double)); // 32768*8*4 B

    hipMemsetAsync(d_out, 0, (size_t)out_size * sizeof(float), stream);
    norm_kernel<<<dim3(B_ * N_ / 4), 256, 0, stream>>>(tok, invn);
    sim_topk_kernel<<<dim3(16, 32), 256, 0, stream>>>(tok, invn, topk);
    mutual_kernel<<<dim3(B_ * N_ * K_ / 256), 256, 0, stream>>>(topk, out);
}

// Round 2
// 575.380 us; speedup vs baseline: 1.9398x; 1.9398x over previous
//
#include <hip/hip_runtime.h>
#include <math.h>
#include <stdint.h>

#define B_ 32
#define N_ 1024
#define D_ 256
#define K_ 8
#define CAND 12

typedef unsigned short u16;
typedef __attribute__((ext_vector_type(8))) short s16x8;   // 8 bf16 (4 VGPRs)
typedef __attribute__((ext_vector_type(16))) float f32x16; // 32x32 accumulator

__device__ inline void cp16(const void* g, void* l) {
    // async global->LDS, 16B/lane; LDS dest = wave-uniform base + lane*16
    __builtin_amdgcn_global_load_lds((const __attribute__((address_space(1))) void*)g,
                                     (__attribute__((address_space(3))) void*)l, 16, 0, 0);
}

__device__ inline u16 f2bf(float f) {               // RNE float->bf16 bits
    uint32_t u = __float_as_uint(f);
    return (u16)((u + 0x7fffu + ((u >> 16) & 1u)) >> 16);
}
__device__ inline float bf2f(u16 h) { return __uint_as_float(((uint32_t)h) << 16); }

// ------------- Kernel 1: fp64 inverse norms + normalized bf16 hi/lo -------------
__global__ __launch_bounds__(256) void prep_kernel(const float* __restrict__ tok,
                                                   double* __restrict__ invn,
                                                   u16* __restrict__ xhi,
                                                   u16* __restrict__ xlo) {
    const int tid = threadIdx.x;
    const int wave = tid >> 6, lane = tid & 63;
    const int row = blockIdx.x * 4 + wave;          // 32768 rows
    const float4 v = *reinterpret_cast<const float4*>(tok + (size_t)row * D_ + lane * 4);
    double s = (double)v.x * v.x + (double)v.y * v.y +
               (double)v.z * v.z + (double)v.w * v.w;
    #pragma unroll
    for (int off = 32; off > 0; off >>= 1) s += __shfl_xor(s, off, 64);
    const double inv = 1.0 / (sqrt(s) + 1e-8);
    if (lane == 0) invn[row] = inv;
    const float x0 = (float)(v.x * inv), x1 = (float)(v.y * inv),
                x2 = (float)(v.z * inv), x3 = (float)(v.w * inv);
    ushort4 h, l;
    h.x = f2bf(x0); l.x = f2bf(x0 - bf2f(h.x));
    h.y = f2bf(x1); l.y = f2bf(x1 - bf2f(h.y));
    h.z = f2bf(x2); l.z = f2bf(x2 - bf2f(h.z));
    h.w = f2bf(x3); l.w = f2bf(x3 - bf2f(h.w));
    *reinterpret_cast<ushort4*>(xhi + (size_t)row * D_ + lane * 4) = h;
    *reinterpret_cast<ushort4*>(xlo + (size_t)row * D_ + lane * 4) = l;
}

// ------------- Kernel 2: MFMA sim + fused top-12 + fp64 rescore -------------
// grid (16, 32): blockIdx.x = 64-row i-strip, blockIdx.y = batch.
// LDS carve (49,664 B -> 3 blocks/CU by LDS):
//   [0,32768)      Ah/Al/Bh/Bl tiles, 8KB each: [64 rows][8 x 16B chunks], XOR-swizzled
//   [32768,49664)  Sim [64][66] float
//   aliases: pv[256][12]f / pi[256][12]i over tiles; mj[64][12]i + dv[64][12]d over Sim
__global__ __launch_bounds__(256) void sim_topk_kernel(const u16* __restrict__ Xhi,
                                                       const u16* __restrict__ Xlo,
                                                       const float* __restrict__ tok,
                                                       const double* __restrict__ invn,
                                                       int* __restrict__ topk) {
    __shared__ __align__(16) char smem[49664];
    char* tiles = smem;
    float*  SimT = (float*)(smem + 32768);
    float*  pv   = (float*)(smem);
    int*    pi   = (int*)(smem + 12288);
    int*    mj   = (int*)(smem + 32768);
    double* dv   = (double*)(smem + 35840);

    const int b  = blockIdx.y;
    const int i0 = blockIdx.x * 64;
    const int tid = threadIdx.x;
    const int w = tid >> 6, lane = tid & 63;
    const int mq = w >> 1, nq = w & 1;              // 2x2 wave grid of 32x32 tiles
    const int half = lane >> 5;

    const u16* XhiB = Xhi + (size_t)b * N_ * D_;
    const u16* XloB = Xlo + (size_t)b * N_ * D_;

    // staging role: wave 0->Ah, 1->Al, 2->Bh, 3->Bl (8 x 1KB cp16 each per stage)
    const u16* ssrc = (w & 1) ? XloB : XhiB;
    char* sdst = tiles + w * 8192;
    const int isA = (w < 2);
    const int srr = lane >> 3, spp = lane & 7;      // row-in-group, chunk-pos

    // fragment rows (fixed per lane)
    const int ra = mq * 32 + (lane & 31);
    const int rb = nq * 32 + (lane & 31);
    const int xa = ra & 7, xb = rb & 7;             // XOR keys

    // scan identity: 4 threads per row, 16 cols each
    const int sr = tid & 63, sq = tid >> 6;
    const int gi_scan = i0 + sr;

    float vals[CAND]; int idxs[CAND];
    #pragma unroll
    for (int c = 0; c < CAND; ++c) { vals[c] = -INFINITY; idxs[c] = -1; }

    for (int jt = 0; jt < 16; ++jt) {
        const int j0 = jt * 64;
        f32x16 acc;
        #pragma unroll
        for (int c = 0; c < 16; ++c) acc[c] = 0.0f;

        for (int kc = 0; kc < 4; ++kc) {
            const int k0 = kc * 64;
            __syncthreads();                        // tiles free for overwrite
            const int rowbase = isA ? i0 : j0;
            #pragma unroll
            for (int t = 0; t < 8; ++t) {
                const int r = t * 8 + srr;
                const int c = spp ^ (r & 7);        // gather source chunk for swizzle
                cp16(ssrc + (size_t)(rowbase + r) * D_ + k0 + c * 8, sdst + t * 1024);
            }
            __syncthreads();                        // drain vmcnt + barrier
            #pragma unroll
            for (int ks = 0; ks < 4; ++ks) {
                const int ca = ((ks * 2 + half) ^ xa) * 16;
                const int cb = ((ks * 2 + half) ^ xb) * 16;
                const s16x8 ah = *(const s16x8*)(tiles +         ra * 128 + ca);
                const s16x8 al = *(const s16x8*)(tiles +  8192 + ra * 128 + ca);
                const s16x8 bh = *(const s16x8*)(tiles + 16384 + rb * 128 + cb);
                const s16x8 bl = *(const s16x8*)(tiles + 24576 + rb * 128 + cb);
                acc = __builtin_amdgcn_mfma_f32_32x32x16_bf16(ah, bh, acc, 0, 0, 0);
                acc = __builtin_amdgcn_mfma_f32_32x32x16_bf16(ah, bl, acc, 0, 0, 0);
                acc = __builtin_amdgcn_mfma_f32_32x32x16_bf16(al, bh, acc, 0, 0, 0);
            }
        }

        // C/D layout: col=lane&31, row=(reg&3)+8*(reg>>2)+4*(lane>>5)  [m74/m101]
        {
            const int col = nq * 32 + (lane & 31);
            const int rbase = mq * 32 + 4 * half;
            #pragma unroll
            for (int reg = 0; reg < 16; ++reg)
                SimT[(rbase + (reg & 3) + 8 * (reg >> 2)) * 66 + col] = acc[reg];
        }
        __syncthreads();

        // parallel scan: thread owns (row sr, col quarter sq)
        #pragma unroll 4
        for (int c = 0; c < 16; ++c) {
            const int jl = sq * 16 + c;
            const int gj = j0 + jl;
            const float v = SimT[sr * 66 + jl];
            if (gj != gi_scan && v > vals[CAND - 1]) {
                float cv = v; int ci = gj;
                #pragma unroll
                for (int cc = 0; cc < CAND; ++cc) {
                    if (cv > vals[cc]) {
                        const float tv = vals[cc]; vals[cc] = cv; cv = tv;
                        const int   ti = idxs[cc]; idxs[cc] = ci; ci = ti;
                    }
                }
            }
        }
        // next jt's kc=0 barrier protects SimT before rewrite
    }

    __syncthreads();                                // tiles dead -> alias pv/pi
    #pragma unroll
    for (int c = 0; c < CAND; ++c) { pv[tid * CAND + c] = vals[c]; pi[tid * CAND + c] = idxs[c]; }
    __syncthreads();

    // 4-way merge of sorted partial lists -> top-12 per row
    if (tid < 64) {
        int p0 = 0, p1 = 0, p2 = 0, p3 = 0;
        #pragma unroll
        for (int o = 0; o < CAND; ++o) {
            const float v0 = pv[(tid      ) * CAND + p0];
            const float v1 = pv[(tid +  64) * CAND + p1];
            const float v2 = pv[(tid + 128) * CAND + p2];
            const float v3 = pv[(tid + 192) * CAND + p3];
            int bg = 0; float bv = v0;
            if (v1 > bv) { bv = v1; bg = 1; }
            if (v2 > bv) { bv = v2; bg = 2; }
            if (v3 > bv) { bv = v3; bg = 3; }
            const int pp = (bg == 0) ? p0 : (bg == 1) ? p1 : (bg == 2) ? p2 : p3;
            mj[tid * CAND + o] = pi[(tid + 64 * bg) * CAND + pp];
            p0 += (bg == 0); p1 += (bg == 1); p2 += (bg == 2); p3 += (bg == 3);
        }
    }
    __syncthreads();

    // fp64 rescore, parallel over 3 groups of 4 candidates
    const float*  tokB = tok  + (size_t)b * N_ * D_;
    const double* invB = invn + b * N_;
    if (tid < 192) {
        const int r = tid & 63, g = tid >> 6;
        const int gi = i0 + r;
        const float* qi = tokB + (size_t)gi * D_;
        const double di = invB[gi];
        #pragma unroll 1
        for (int cc = 0; cc < 4; ++cc) {
            const int c = g * 4 + cc;
            const int j = mj[r * CAND + c];
            const float* qj = tokB + (size_t)j * D_;
            double s = 0.0;
            for (int d = 0; d < D_; d += 4) {
                const float4 x = *reinterpret_cast<const float4*>(qi + d);
                const float4 y = *reinterpret_cast<const float4*>(qj + d);
                s += (double)x.x * y.x + (double)x.y * y.y +
                     (double)x.z * y.z + (double)x.w * y.w;
            }
            dv[r * CAND + c] = s * di * invB[j];
        }
    }
    __syncthreads();

    // exact top-8 by fp64 rank (ties -> lower index, matching lax.top_k)
    if (tid < 64) {
        const int out_base = (b * N_ + i0 + tid) * K_;
        #pragma unroll 1
        for (int c = 0; c < CAND; ++c) {
            const double dc = dv[tid * CAND + c]; const int jc = mj[tid * CAND + c];
            int rank = 0;
            #pragma unroll 1
            for (int c2 = 0; c2 < CAND; ++c2) {
                if (c2 == c) continue;
                const double d2 = dv[tid * CAND + c2]; const int j2 = mj[tid * CAND + c2];
                if (d2 > dc || (d2 == dc && j2 < jc)) ++rank;
            }
            if (rank < K_) topk[out_base + rank] = jc;
        }
    }
}

// ------------- Kernel 3: mutual filter + scatter 1.0 -------------
__global__ __launch_bounds__(256) void mutual_kernel(const int* __restrict__ topk,
                                                     float* __restrict__ out) {
    const int gid = blockIdx.x * 256 + threadIdx.x;   // 32768*8 threads
    const int row = gid >> 3, s = gid & 7;
    const int j = topk[row * K_ + s];
    const int i = row & (N_ - 1);
    const int* tj = topk + ((row & ~(N_ - 1)) + j) * K_;
    bool m = false;
    #pragma unroll
    for (int u = 0; u < K_; ++u) m = m || (tj[u] == i);
    if (m) out[(size_t)row * N_ + j] = 1.0f;
}

extern "C" void kernel_launch(void* const* d_in, const int* in_sizes, int n_in,
                              void* d_out, int out_size, void* d_ws, size_t ws_size,
                              hipStream_t stream) {
    const float* tok = (const float*)d_in[0];
    float* out = (float*)d_out;
    double* invn = (double*)d_ws;                                  // 256 KB
    int* topk = (int*)((char*)d_ws + (size_t)B_ * N_ * sizeof(double)); // 1 MB
    // bf16 hi/lo scratch lives in d_out (32 MB of 128 MB) until memset
    u16* xhi = (u16*)d_out;
    u16* xlo = xhi + (size_t)B_ * N_ * D_;

    prep_kernel<<<dim3(B_ * N_ / 4), 256, 0, stream>>>(tok, invn, xhi, xlo);
    sim_topk_kernel<<<dim3(16, 32), 256, 0, stream>>>(xhi, xlo, tok, invn, topk);
    hipMemsetAsync(d_out, 0, (size_t)out_size * sizeof(float), stream);
    mutual_kernel<<<dim3(B_ * N_ * K_ / 256), 256, 0, stream>>>(topk, out);
}